// Round 5
// baseline (87163.898 us; speedup 1.0000x reference)
//
#include <hip/hip_runtime.h>

#define T_STEPS 2048
#define NBATCH  32
#define IN_DIM  64
#define RES     1024
#define LEAKF   0.3f

typedef float f32x4 __attribute__((ext_vector_type(4)));

// ---------------------------------------------------------------------------
// Round 5: one batch = one block. No inter-block communication at all.
// Rationale: R1-R3 proved any agent-scope exchange costs ~10us/step no matter
// the protocol; R4's sub-agent-scope fast path deadlocked (unproven sc0
// visibility). Intra-block LDS is the only proven-fast domain, so the whole
// recurrence for one batch runs inside a single 1024-thread block:
//   - state s[1024] in LDS (4 KB), two __syncthreads() per step
//   - thread (kq = tid>>8, cq = tid&255) computes the partial dot over
//     k in [256*kq, 256*kq+256) for 4 consecutive columns c = 4*cq..4*cq+3
//   - W rows loaded as float4 (perfectly coalesced per wave, L2-resident:
//     all 32 blocks stream the same 4 MB every step)
//   - s read via wave-uniform LDS broadcast (conflict-free)
//   - input fragment (16 floats/thread) prefetched one step ahead into regs;
//     its 16-row Win partial is folded into the same accumulator
//   - finalize: one column per thread (all 16 waves), tanh + leak, write
//     LDS state + out
// Per-step issue floor: 1088 FMA/thread x 2cy x 4 waves/SIMD ~= 8.7k cy
// ~= 3.6us; W L2 stream ~3.7us/XCD overlapped. No workspace, replay-safe.
// ---------------------------------------------------------------------------
__global__ __launch_bounds__(1024, 1) void esn_batch(
    const float* __restrict__ inp,   // [32][2048][64]
    const float* __restrict__ Win,   // [64][1024]
    const float* __restrict__ Wres,  // [1024][1024]
    float* __restrict__ out)         // [32][2048][1024]
{
    const int tid = threadIdx.x;
    const int b   = blockIdx.x;      // batch
    const int kq  = tid >> 8;        // 0..3   : k-quarter [256*kq, 256*kq+256)
    const int cq  = tid & 255;       // 0..255 : column group of 4
    const int c4  = cq << 2;
    const int kb  = kq << 8;

    __shared__ __align__(16) float s[RES];          // state s_{t-1}
    __shared__ __align__(16) float pl[4][RES + 8];  // k-quarter partials

    if (tid < 256) {
        const f32x4 z = {0.f, 0.f, 0.f, 0.f};
        *reinterpret_cast<f32x4*>(s + (tid << 2)) = z;
    }
    __syncthreads();

    const float* inb  = inp + (size_t)b * T_STEPS * IN_DIM + (kq << 4);
    const float* WinP = Win + (size_t)(kq << 4) * RES + c4;
    const float* Wp   = Wres + (size_t)kb * RES + c4;
    float*       outb = out + (size_t)b * T_STEPS * RES;

    // Current-step input fragment: inp[b][t][16*kq .. 16*kq+15].
    f32x4 i0 = *reinterpret_cast<const f32x4*>(inb + 0);
    f32x4 i1 = *reinterpret_cast<const f32x4*>(inb + 4);
    f32x4 i2 = *reinterpret_cast<const f32x4*>(inb + 8);
    f32x4 i3 = *reinterpret_cast<const f32x4*>(inb + 12);

    for (int t = 0; t < T_STEPS; ++t) {
        // Prefetch next step's input fragment; hides under the GEMM below.
        f32x4 n0, n1, n2, n3;
        const bool more = (t + 1 < T_STEPS);
        if (more) {
            n0 = *reinterpret_cast<const f32x4*>(inb + IN_DIM + 0);
            n1 = *reinterpret_cast<const f32x4*>(inb + IN_DIM + 4);
            n2 = *reinterpret_cast<const f32x4*>(inb + IN_DIM + 8);
            n3 = *reinterpret_cast<const f32x4*>(inb + IN_DIM + 12);
        }

        // ---- Recurrent partial: acc[r] = sum_{k in quarter} s[k]*W[k][c4+r].
        f32x4 acc = {0.f, 0.f, 0.f, 0.f};
        #pragma unroll 4
        for (int jj = 0; jj < 64; ++jj) {
            const f32x4 s4 = *reinterpret_cast<const f32x4*>(s + kb + (jj << 2));
            const float* wr = Wp + (size_t)(jj << 2) * RES;
            const f32x4 w0 = *reinterpret_cast<const f32x4*>(wr);
            const f32x4 w1 = *reinterpret_cast<const f32x4*>(wr + RES);
            const f32x4 w2 = *reinterpret_cast<const f32x4*>(wr + 2 * RES);
            const f32x4 w3 = *reinterpret_cast<const f32x4*>(wr + 3 * RES);
            acc = w0 * s4.x + acc;
            acc = w1 * s4.y + acc;
            acc = w2 * s4.z + acc;
            acc = w3 * s4.w + acc;
        }

        // ---- Input-projection partial over this kq's 16 rows of Win.
        {
            const float* wi = WinP;
            acc = *reinterpret_cast<const f32x4*>(wi           ) * i0.x + acc;
            acc = *reinterpret_cast<const f32x4*>(wi +  1 * RES) * i0.y + acc;
            acc = *reinterpret_cast<const f32x4*>(wi +  2 * RES) * i0.z + acc;
            acc = *reinterpret_cast<const f32x4*>(wi +  3 * RES) * i0.w + acc;
            acc = *reinterpret_cast<const f32x4*>(wi +  4 * RES) * i1.x + acc;
            acc = *reinterpret_cast<const f32x4*>(wi +  5 * RES) * i1.y + acc;
            acc = *reinterpret_cast<const f32x4*>(wi +  6 * RES) * i1.z + acc;
            acc = *reinterpret_cast<const f32x4*>(wi +  7 * RES) * i1.w + acc;
            acc = *reinterpret_cast<const f32x4*>(wi +  8 * RES) * i2.x + acc;
            acc = *reinterpret_cast<const f32x4*>(wi +  9 * RES) * i2.y + acc;
            acc = *reinterpret_cast<const f32x4*>(wi + 10 * RES) * i2.z + acc;
            acc = *reinterpret_cast<const f32x4*>(wi + 11 * RES) * i2.w + acc;
            acc = *reinterpret_cast<const f32x4*>(wi + 12 * RES) * i3.x + acc;
            acc = *reinterpret_cast<const f32x4*>(wi + 13 * RES) * i3.y + acc;
            acc = *reinterpret_cast<const f32x4*>(wi + 14 * RES) * i3.z + acc;
            acc = *reinterpret_cast<const f32x4*>(wi + 15 * RES) * i3.w + acc;
        }

        *reinterpret_cast<f32x4*>(&pl[kq][c4]) = acc;

        if (more) { i0 = n0; i1 = n1; i2 = n2; i3 = n3; inb += IN_DIM; }
        __syncthreads();   // partials visible; all s-reads of this step done

        // ---- Finalize: one column per thread across all 16 waves.
        // Each thread reads/writes only s[tid] -> no intra-phase hazard.
        {
            const float sum = pl[0][tid] + pl[1][tid] + pl[2][tid] + pl[3][tid];
            const float nw  = tanhf(sum);
            const float sn  = fmaf(1.0f - LEAKF, s[tid], LEAKF * nw);
            outb[(size_t)t * RES + tid] = sn;
            s[tid] = sn;
        }
        __syncthreads();   // new state visible; pl free for overwrite
    }
}

extern "C" void kernel_launch(void* const* d_in, const int* in_sizes, int n_in,
                              void* d_out, int out_size, void* d_ws, size_t ws_size,
                              hipStream_t stream)
{
    const float* inp  = (const float*)d_in[0];   // [32,2048,64]
    const float* Win  = (const float*)d_in[1];   // [64,1024]
    const float* Wres = (const float*)d_in[2];   // [1024,1024]
    float* out = (float*)d_out;                  // [32,2048,1024]

    // One block per batch; no workspace, no cross-launch state, replay-safe.
    hipLaunchKernelGGL(esn_batch, dim3(NBATCH), dim3(1024), 0, stream,
                       inp, Win, Wres, out);
    (void)d_ws; (void)ws_size; (void)in_sizes; (void)n_in;
}

// Round 6
// 21386.681 us; speedup vs baseline: 4.0756x; 4.0756x over previous
//
#include <hip/hip_runtime.h>

#define T_STEPS 2048
#define NBATCH  32
#define IN_DIM  64
#define RES     1024
#define LEAKF   0.3f
#define NCG     64   // column groups (16 cols each)
#define NBG     4    // batch groups (8 batches each)

typedef unsigned int u32;
typedef unsigned long long u64cp;

// ---------------------------------------------------------------------------
// Round 6: R2's verified compute structure + contention-minimized sync.
// R1/R2 spun 16K threads on ~256B of flags through the coherence point; the
// poll storm itself was the ~10us/step wall (R2 changed everything but the
// poll and changed nothing; R3 doubled poll traffic and doubled time).
// Now: ONE monotonic counter per batch-group (4 counters, 256B apart).
//   producer: tid0 atomicAdd(+1) after the store-drain barrier (once/step)
//   consumer: tid0 polls cnt >= 64*t with s_sleep backoff, then barrier
// Poll pressure drops ~4 orders of magnitude; everything else is the proven
// R1/R2 protocol (relaxed agent-scope state stores, vmcnt-drained before the
// publish; staged 32KB state fetch; identical FMA/reduce order).
// ---------------------------------------------------------------------------
__global__ __launch_bounds__(256, 1) void esn_persist(
    const float* __restrict__ inp,   // [32][2048][64]
    const float* __restrict__ Win,   // [64][1024]
    const float* __restrict__ Wres,  // [1024][1024]
    float* __restrict__ out,         // [32][2048][1024]
    float* __restrict__ sC,          // ws+1KB: [4][2][1024][8] compact state
    u32* __restrict__ cnts)          // ws: 4 counters, 64 u32 (256B) apart
{
    const int tid   = threadIdx.x;
    const int c_loc = tid & 15;
    const int ks    = tid >> 4;            // 0..15 : k-chunk [64*ks, 64*ks+64)
    const int cg    = blockIdx.x;          // 0..63
    const int bg    = blockIdx.y;          // 0..3
    const int c0    = cg * 16;
    const int b0    = bg * 8;
    const int c     = c0 + c_loc;

    // Hoist this thread's Wres slice into registers: w[j] = Wres[ks*64+j][c].
    float w[64];
    {
        const float* wp = Wres + (size_t)(ks * 64) * RES + c;
        #pragma unroll
        for (int j = 0; j < 64; ++j) w[j] = wp[(size_t)j * RES];
    }

    // Staged state: row k (8 floats, 32 B) at byte addr k*32 + (k>>6)*16.
    // The +16B pad per 64-row group puts the 4 ks-groups of a wave on
    // distinct banks -> conflict-free broadcast reads.
    __shared__ __align__(16) float sst[8256];   // 33 KB
    __shared__ float pl[16][8][17];             // k-partial reduce, 8.7 KB

    u32* cnt = cnts + bg * 64;             // this group's arrival counter
    float* sCb = sC + (size_t)bg * 2 * RES * 8;

    const int fb = tid >> 4;               // finalize batch lane (tid < 128)
    float s_prev = 0.f;                    // register-carried state (b0+fb, c)

    for (int t = 0; t < T_STEPS; ++t) {
        float* sCr = sCb + ((t & 1) ^ 1) * (RES * 8);  // state t-1
        float* sCw = sCb + (t & 1) * (RES * 8);        // state t

        // ---- Phase A: input projection (state-independent; overlaps wait)
        float x = 0.f;
        if (tid < 128) {
            const float* inb = inp + ((size_t)(b0 + fb) * T_STEPS + t) * IN_DIM;
            #pragma unroll
            for (int i = 0; i < IN_DIM; i += 4) {
                const float4 v = *reinterpret_cast<const float4*>(inb + i);
                x = fmaf(v.x, Win[(size_t)(i + 0) * RES + c], x);
                x = fmaf(v.y, Win[(size_t)(i + 1) * RES + c], x);
                x = fmaf(v.z, Win[(size_t)(i + 2) * RES + c], x);
                x = fmaf(v.w, Win[(size_t)(i + 3) * RES + c], x);
            }
        }

        if (t > 0) {
            // ---- Phase B: single-thread low-rate wait for all 64 producers
            // of step t-1 (monotonic: cnt reaches 64*t exactly when every
            // producer has published step t-1).
            if (tid == 0) {
                const u32 tgt = 64u * (u32)t;
                while (__hip_atomic_load(cnt, __ATOMIC_RELAXED,
                                         __HIP_MEMORY_SCOPE_AGENT) < tgt) {
                    __builtin_amdgcn_s_sleep(1);
                }
            }
            __syncthreads();

            // ---- Phase B2: cooperative stage of the 32 KB state slab.
            // Chunk m = i*256+tid covers global floats [m*4, m*4+4) and LDS
            // byte addr m*16 + (m>>7)*16 (row-group padding folded in).
            #pragma unroll
            for (int i = 0; i < 8; ++i) {
                const int m = i * 256 + tid;
                u64cp lo = __hip_atomic_load((u64cp*)(sCr + (size_t)m * 4),
                                             __ATOMIC_RELAXED, __HIP_MEMORY_SCOPE_AGENT);
                u64cp hi = __hip_atomic_load((u64cp*)(sCr + (size_t)m * 4 + 2),
                                             __ATOMIC_RELAXED, __HIP_MEMORY_SCOPE_AGENT);
                float4* dst = (float4*)((char*)sst + (size_t)m * 16 + (m >> 7) * 16);
                *dst = make_float4(__uint_as_float((unsigned)(lo       )),
                                   __uint_as_float((unsigned)(lo >> 32u)),
                                   __uint_as_float((unsigned)(hi       )),
                                   __uint_as_float((unsigned)(hi >> 32u)));
            }
            __syncthreads();
        }

        // ---- Phase C: acc(b) = sum over k-chunk of W[k][c] * s[k][b], from LDS.
        float acc0 = 0.f, acc1 = 0.f, acc2 = 0.f, acc3 = 0.f;
        float acc4 = 0.f, acc5 = 0.f, acc6 = 0.f, acc7 = 0.f;
        if (t > 0) {
            const char* base = (const char*)sst + (size_t)(ks * 64) * 32 + ks * 16;
            #pragma unroll
            for (int j = 0; j < 64; ++j) {
                const float4 sa = *reinterpret_cast<const float4*>(base + j * 32);
                const float4 sb = *reinterpret_cast<const float4*>(base + j * 32 + 16);
                const float wj = w[j];
                acc0 = fmaf(sa.x, wj, acc0);
                acc1 = fmaf(sa.y, wj, acc1);
                acc2 = fmaf(sa.z, wj, acc2);
                acc3 = fmaf(sa.w, wj, acc3);
                acc4 = fmaf(sb.x, wj, acc4);
                acc5 = fmaf(sb.y, wj, acc5);
                acc6 = fmaf(sb.z, wj, acc6);
                acc7 = fmaf(sb.w, wj, acc7);
            }
        }

        // ---- Phase D: 16-way k-reduce through LDS, then finalize.
        pl[ks][0][c_loc] = acc0;
        pl[ks][1][c_loc] = acc1;
        pl[ks][2][c_loc] = acc2;
        pl[ks][3][c_loc] = acc3;
        pl[ks][4][c_loc] = acc4;
        pl[ks][5][c_loc] = acc5;
        pl[ks][6][c_loc] = acc6;
        pl[ks][7][c_loc] = acc7;
        __syncthreads();

        if (tid < 128) {
            float sum = 0.f;
            #pragma unroll
            for (int q = 0; q < 16; ++q) sum += pl[q][fb][c_loc];

            const float nw = tanhf(x + sum);
            const float sn = fmaf(1.0f - LEAKF, s_prev, LEAKF * nw);
            s_prev = sn;

            out[((size_t)(b0 + fb) * T_STEPS + t) * RES + c] = sn;
            __hip_atomic_store(sCw + (size_t)c * 8 + fb, sn,
                               __ATOMIC_RELAXED, __HIP_MEMORY_SCOPE_AGENT);
        }
        // Barrier: every wave drains vmcnt(0) before passing -> all 128 state
        // stores of this block are at the coherence point afterwards.
        __syncthreads();

        // ---- Phase E: publish completion of step t (one add per block).
        if (tid == 0)
            __hip_atomic_fetch_add(cnt, 1u, __ATOMIC_RELAXED,
                                   __HIP_MEMORY_SCOPE_AGENT);
    }
}

// ---------------------------------------------------------------------------
// Fallback: proven per-step kernel (used only if ws too small).
// ---------------------------------------------------------------------------
__global__ __launch_bounds__(256) void esn_step(
    const float* __restrict__ inp,
    const float* __restrict__ Win,
    const float* __restrict__ Wres,
    float* __restrict__ out,
    float* __restrict__ sT,
    int t)
{
    const int tid   = threadIdx.x;
    const int c_loc = tid & 15;
    const int ks    = tid >> 4;
    const int c0    = blockIdx.x * 16;
    const int b0    = blockIdx.y * 8;
    const int c     = c0 + c_loc;

    const float* sTr = sT + ((t & 1) ^ 1) * (RES * NBATCH);
    float*       sTw = sT + (t & 1) * (RES * NBATCH);

    float acc0 = 0.f, acc1 = 0.f, acc2 = 0.f, acc3 = 0.f;
    float acc4 = 0.f, acc5 = 0.f, acc6 = 0.f, acc7 = 0.f;

    if (t > 0) {
        const int kbeg = ks * 64;
        const float* wp = Wres + (size_t)kbeg * RES + c;
        const float* sp = sTr + kbeg * NBATCH + b0;
        #pragma unroll 4
        for (int j = 0; j < 64; ++j) {
            const float w = wp[(size_t)j * RES];
            const float4 sa = *reinterpret_cast<const float4*>(sp + j * NBATCH);
            const float4 sb = *reinterpret_cast<const float4*>(sp + j * NBATCH + 4);
            acc0 = fmaf(sa.x, w, acc0);
            acc1 = fmaf(sa.y, w, acc1);
            acc2 = fmaf(sa.z, w, acc2);
            acc3 = fmaf(sa.w, w, acc3);
            acc4 = fmaf(sb.x, w, acc4);
            acc5 = fmaf(sb.y, w, acc5);
            acc6 = fmaf(sb.z, w, acc6);
            acc7 = fmaf(sb.w, w, acc7);
        }
    }

    __shared__ float plf[16][8][17];
    plf[ks][0][c_loc] = acc0;
    plf[ks][1][c_loc] = acc1;
    plf[ks][2][c_loc] = acc2;
    plf[ks][3][c_loc] = acc3;
    plf[ks][4][c_loc] = acc4;
    plf[ks][5][c_loc] = acc5;
    plf[ks][6][c_loc] = acc6;
    plf[ks][7][c_loc] = acc7;
    __syncthreads();

    if (tid < 128) {
        const int b   = tid >> 4;
        const int cl  = tid & 15;
        const int cgl = c0 + cl;
        const int bgl = b0 + b;

        float sum = 0.f;
        #pragma unroll
        for (int q = 0; q < 16; ++q) sum += plf[q][b][cl];

        const float* inb = inp + ((size_t)bgl * T_STEPS + t) * IN_DIM;
        float x = 0.f;
        #pragma unroll 8
        for (int i = 0; i < IN_DIM; ++i)
            x = fmaf(inb[i], Win[(size_t)i * RES + cgl], x);

        const float nw = tanhf(x + sum);
        const float spv = (t > 0) ? sTr[cgl * NBATCH + bgl] : 0.f;
        const float sn = fmaf(1.0f - LEAKF, spv, LEAKF * nw);

        out[((size_t)bgl * T_STEPS + t) * RES + cgl] = sn;
        sTw[cgl * NBATCH + bgl] = sn;
    }
}

extern "C" void kernel_launch(void* const* d_in, const int* in_sizes, int n_in,
                              void* d_out, int out_size, void* d_ws, size_t ws_size,
                              hipStream_t stream)
{
    const float* inp  = (const float*)d_in[0];   // [32,2048,64]
    const float* Win  = (const float*)d_in[1];   // [64,1024]
    const float* Wres = (const float*)d_in[2];   // [1024,1024]
    float* out = (float*)d_out;                  // [32,2048,1024]

    const size_t cntBytes   = 1024;                                       // 4 x 256B
    const size_t stateBytes = (size_t)NBG * 2 * RES * 8 * sizeof(float);  // 256 KB

    if (ws_size >= cntBytes + stateBytes) {
        u32*   cnts = (u32*)d_ws;
        float* sC   = (float*)((char*)d_ws + cntBytes);
        hipMemsetAsync(cnts, 0, cntBytes, stream);   // re-zeroed every replay
        hipLaunchKernelGGL(esn_persist, dim3(NCG, NBG), dim3(256), 0, stream,
                           inp, Win, Wres, out, sC, cnts);
        return;
    }

    // Workspace too small: proven per-step path.
    float* sT = (float*)d_ws;   // [2][1024][32]
    dim3 grid(64, 4), blk(256);
    for (int t = 0; t < T_STEPS; ++t) {
        hipLaunchKernelGGL(esn_step, grid, blk, 0, stream,
                           inp, Win, Wres, out, sT, t);
    }
}